// Round 10
// baseline (564.953 us; speedup 1.0000x reference)
//
#include <hip/hip_runtime.h>

#define S_LEN    2048
#define DK       64
#define N_BH     32
#define NTHREADS 512

typedef float              f32x4  __attribute__((ext_vector_type(4)));
typedef int                i32x4  __attribute__((ext_vector_type(4)));
typedef short              bf16x8 __attribute__((ext_vector_type(8)));
typedef unsigned short     u16x8  __attribute__((ext_vector_type(8)));
typedef unsigned int       u32x4  __attribute__((ext_vector_type(4)));
typedef unsigned long long u64;

__device__ __forceinline__ unsigned short f2bf(float f) {
    unsigned u = __builtin_bit_cast(unsigned, f);
    u += 0x7fffu + ((u >> 16) & 1u);
    return (unsigned short)(u >> 16);
}
__device__ __forceinline__ float bf2f(unsigned short h) {
    unsigned u = ((unsigned)h) << 16;
    return __builtin_bit_cast(float, u);
}
__device__ __forceinline__ unsigned pack_bf2(float a, float b) {
    return (unsigned)f2bf(a) | ((unsigned)f2bf(b) << 16);
}

// ---------------- prep kernels: LDS-image bf16 layouts in d_ws ----------------
// Q2[(bh*128+tile)*1024 + lane*8 + j] = q[bh][tile*16+m][ks*32+g*8+j], lane=g*16+m, +512 for ks=1
__global__ void prep_q(const float* __restrict__ q, unsigned short* __restrict__ Q2) {
    const int bq = blockIdx.x;                 // bh*128 + tile
    const int tx = threadIdx.x;                // 128 threads: ks(1)|g(2)|m(4)
    const int ks = tx >> 6, g = (tx >> 4) & 3, m = tx & 15;
    const long row = ((long)(bq >> 7) * S_LEN + (bq & 127) * 16 + m);
    const float* p = q + row * DK + ks * 32 + g * 8;
    f32x4 x0 = *(const f32x4*)p, x1 = *(const f32x4*)(p + 4);
    u16x8 o;
    o[0]=f2bf(x0.x); o[1]=f2bf(x0.y); o[2]=f2bf(x0.z); o[3]=f2bf(x0.w);
    o[4]=f2bf(x1.x); o[5]=f2bf(x1.y); o[6]=f2bf(x1.z); o[7]=f2bf(x1.w);
    *(u16x8*)(Q2 + (long)bq * 1024 + (ks * 512) + ((g * 16 + m) * 8)) = o;
}

// K2 image: per (bh, panel p of 128 t): image[(t*64 + d) ^ ((t&7)<<3)] = K[t_global][d]
__global__ void prep_k(const float* __restrict__ k, unsigned short* __restrict__ K2) {
    __shared__ float t[64][65];
    const int bh = blockIdx.x >> 5, s0 = (blockIdx.x & 31) << 6;
    const int tx = threadIdx.x;
    const float* kb = k + (long)bh * DK * S_LEN;
    #pragma unroll
    for (int i = 0; i < 16; ++i) {
        const int d = (i << 2) + (tx >> 6), s = tx & 63;
        t[d][s] = kb[(long)d * S_LEN + s0 + s];
    }
    __syncthreads();
    #pragma unroll
    for (int it = 0; it < 2; ++it) {
        const int f = it * 256 + tx;           // 512 frags: t(6b)|d0(3b)
        const int tl = f >> 3, d0 = f & 7;
        const int tg = s0 + tl;
        const int p = tg >> 7, tp = tg & 127;
        u16x8 o;
        #pragma unroll
        for (int j = 0; j < 8; ++j) o[j] = f2bf(t[d0 * 8 + j][tl]);
        const int idx = (tp * 64 + d0 * 8) ^ ((tp & 7) << 3);
        *(u16x8*)(K2 + ((long)(bh * 16 + p) << 13) + idx) = o;
    }
}

// V2 image: per (bh, panel p): image[(d*128 + t) ^ ((d&7)<<3)] = V[t_global][d]
__global__ void prep_v(const float* __restrict__ v, unsigned short* __restrict__ V2) {
    __shared__ float t[64][65];
    const int bh = blockIdx.x >> 5, s0 = (blockIdx.x & 31) << 6;
    const int tx = threadIdx.x;
    #pragma unroll
    for (int i = 0; i < 16; ++i) {
        const int s = (i << 2) + (tx >> 6), d = tx & 63;
        t[s][d] = v[((long)bh * S_LEN + s0 + s) * DK + d];
    }
    __syncthreads();
    #pragma unroll
    for (int it = 0; it < 2; ++it) {
        const int f = it * 256 + tx;           // 512 frags: d(6b)|t8i(3b)
        const int d = f >> 3, t8 = (f & 7) * 8;
        const int tg8 = s0 + t8;
        const int p = tg8 >> 7, tp8 = tg8 & 127;
        u16x8 o;
        #pragma unroll
        for (int j = 0; j < 8; ++j) o[j] = f2bf(t[t8 + j][d]);
        const int idx = (d * 128 + tp8) ^ ((d & 7) << 3);
        *(u16x8*)(V2 + ((long)(bh * 16 + p) << 13) + idx) = o;
    }
}

// ---------------------------- main attention kernel ----------------------------
// 128 q-rows/block, 8 waves x 16 rows each, two passes over 16 K-panels of 128 cols.
template <bool WS>
__global__ __launch_bounds__(NTHREADS, 4)
void sdpa_main(const float* __restrict__ q, const float* __restrict__ k,
               const float* __restrict__ v, const int* __restrict__ mask,
               const unsigned short* __restrict__ Q2,
               const unsigned short* __restrict__ K2,
               const unsigned short* __restrict__ V2,
               float* __restrict__ ctx, float* __restrict__ attn)
{
    __shared__ unsigned short Kbuf[8192];      // 16 KB K panel (swizzled image)
    __shared__ unsigned short Vbuf[8192];      // 16 KB V panel (swizzled image)
    __shared__ u64 Mlds[4096];                 // 32 KB mask bits [wave][chunk][lane]

    const int bid  = blockIdx.x;
    const int bh   = bid & (N_BH - 1);         // same head -> same XCD (512 blocks, 32|8)
    const int qt   = bid >> 5;
    const int tid  = threadIdx.x;
    const int wave = tid >> 6;
    const int lane = tid & 63;
    const int m    = lane & 15;
    const int g    = lane >> 4;
    const long rowbase = (long)bh * S_LEN + qt * 128 + wave * 16;   // wave's 16 rows

    // ---- Q fragment (B operand): Q[col=m][k=ks*32+g*8+j] ----
    bf16x8 qfrag[2];
    if (WS) {
        const unsigned short* qp = Q2 + ((long)(bh * 128 + qt * 8 + wave) << 10) + (lane << 3);
        qfrag[0] = *(const bf16x8*)qp;
        qfrag[1] = *(const bf16x8*)(qp + 512);
    } else {
        const float* qp = q + (rowbase + m) * DK;
        #pragma unroll
        for (int ks = 0; ks < 2; ++ks) {
            const float* p = qp + ks * 32 + g * 8;
            f32x4 x0 = *(const f32x4*)p, x1 = *(const f32x4*)(p + 4);
            qfrag[ks][0]=(short)f2bf(x0.x); qfrag[ks][1]=(short)f2bf(x0.y);
            qfrag[ks][2]=(short)f2bf(x0.z); qfrag[ks][3]=(short)f2bf(x0.w);
            qfrag[ks][4]=(short)f2bf(x1.x); qfrag[ks][5]=(short)f2bf(x1.y);
            qfrag[ks][6]=(short)f2bf(x1.z); qfrag[ks][7]=(short)f2bf(x1.w);
        }
    }

    const int srcA = ((g & 1) << 5) + m;
    const int srcB = srcA + 16;
    const int hi   = g >> 1;

    // QK^T for one 32-col chunk (t_local = ct16a*16 .. +31) -> af-ordered e (unmasked)
    auto qk_chunk = [&](int ct16a) -> u32x4 {
        unsigned pk0e, pk1e, pk0o, pk1o;
        #pragma unroll
        for (int h = 0; h < 2; ++h) {
            const int tl = (ct16a + h) * 16 + m;
            f32x4 acc = {0.f, 0.f, 0.f, 0.f};
            #pragma unroll
            for (int ks = 0; ks < 2; ++ks) {
                const int idx = (tl * 64 + ks * 32 + g * 8) ^ ((tl & 7) << 3);
                const bf16x8 kf = *(const bf16x8*)&Kbuf[idx];
                acc = __builtin_amdgcn_mfma_f32_16x16x32_bf16(kf, qfrag[ks], acc, 0, 0, 0);
            }
            const float e0 = __expf(acc[0] * 0.125f);
            const float e1 = __expf(acc[1] * 0.125f);
            const float e2 = __expf(acc[2] * 0.125f);
            const float e3 = __expf(acc[3] * 0.125f);
            if (h == 0) { pk0e = pack_bf2(e0, e1); pk1e = pack_bf2(e2, e3); }
            else        { pk0o = pack_bf2(e0, e1); pk1o = pack_bf2(e2, e3); }
        }
        const unsigned a0e = (unsigned)__shfl((int)pk0e, srcA);
        const unsigned a0o = (unsigned)__shfl((int)pk0o, srcA);
        const unsigned a1e = (unsigned)__shfl((int)pk1e, srcA);
        const unsigned a1o = (unsigned)__shfl((int)pk1o, srcA);
        const unsigned a2e = (unsigned)__shfl((int)pk0e, srcB);
        const unsigned a2o = (unsigned)__shfl((int)pk0o, srcB);
        const unsigned a3e = (unsigned)__shfl((int)pk1e, srcB);
        const unsigned a3o = (unsigned)__shfl((int)pk1o, srcB);
        u32x4 wv = { hi ? a0o : a0e, hi ? a1o : a1e,
                     hi ? a2o : a2e, hi ? a3o : a3e };
        return wv;
    };

    auto apply_mask = [&](u32x4 wv, unsigned mb) -> u32x4 {
        if (mb & 1u)   wv.x &= 0xFFFF0000u;
        if (mb & 2u)   wv.x &= 0x0000FFFFu;
        if (mb & 4u)   wv.y &= 0xFFFF0000u;
        if (mb & 8u)   wv.y &= 0x0000FFFFu;
        if (mb & 16u)  wv.z &= 0xFFFF0000u;
        if (mb & 32u)  wv.z &= 0x0000FFFFu;
        if (mb & 64u)  wv.w &= 0xFFFF0000u;
        if (mb & 128u) wv.w &= 0x0000FFFFu;
        return wv;
    };

    auto mask_burst = [&](int c) -> u64 {      // coalesced: nibble r = row, lane = 4 cols
        u64 mb = 0;
        const int* mp = mask + rowbase * (long)S_LEN + c * 256 + 4 * lane;
        #pragma unroll
        for (int r = 0; r < 16; ++r) {
            const i32x4 mk = __builtin_nontemporal_load((const i32x4*)(mp + (long)r * S_LEN));
            const unsigned nib = (mk.x ? 1u : 0u) | (mk.y ? 2u : 0u)
                               | (mk.z ? 4u : 0u) | (mk.w ? 8u : 0u);
            mb |= ((u64)nib) << (r * 4);
        }
        return mb;
    };

    auto redist = [&](u64 mbits) -> u64 {      // -> byte b = 32-chunk b, bit i = col b*32+g*8+i
        u64 lm = 0;
        const unsigned mlo = (unsigned)mbits, mhi = (unsigned)(mbits >> 32);
        #pragma unroll
        for (int kt = 0; kt < 8; ++kt) {
            const int sA = kt * 8 + g * 2, sB = sA + 1;
            const unsigned aLo = (unsigned)__shfl((int)mlo, sA);
            const unsigned aHi = (unsigned)__shfl((int)mhi, sA);
            const unsigned bLo = (unsigned)__shfl((int)mlo, sB);
            const unsigned bHi = (unsigned)__shfl((int)mhi, sB);
            const u64 A = ((u64)aHi << 32) | aLo;
            const u64 B = ((u64)bHi << 32) | bLo;
            const unsigned byt = (unsigned)((A >> (4 * m)) & 0xFull)
                               | ((unsigned)((B >> (4 * m)) & 0xFull) << 4);
            lm |= ((u64)byt) << (8 * kt);
        }
        return lm;
    };

    // ================================ PASS 1 ================================
    float rsum = 0.0f;
    u64 lm = redist(mask_burst(0));
    u16x8 kst0, kst1;
    if (WS) {
        const unsigned short* src = K2 + ((long)(bh * 16) << 13) + (tid << 3);
        kst0 = *(const u16x8*)src;
        kst1 = *(const u16x8*)(src + 4096);
    } else {
        const int f0 = tid, f1 = 512 + tid;
        const int tl0 = f0 >> 3, d00 = (f0 & 7) * 8, tl1 = f1 >> 3, d01 = (f1 & 7) * 8;
        #pragma unroll
        for (int j = 0; j < 8; ++j) kst0[j] = f2bf(k[((long)bh * DK + d00 + j) * S_LEN + tl0]);
        #pragma unroll
        for (int j = 0; j < 8; ++j) kst1[j] = f2bf(k[((long)bh * DK + d01 + j) * S_LEN + tl1]);
    }
    for (int p = 0; p < 16; ++p) {
        const int c = p >> 1;
        __syncthreads();
        {   // write panel p (images are pre-swizzled; !WS path swizzles here)
            if (WS) {
                *(u16x8*)&Kbuf[tid * 8]        = kst0;
                *(u16x8*)&Kbuf[4096 + tid * 8] = kst1;
            } else {
                const int f0 = tid, f1 = 512 + tid;
                const int tl0 = f0 >> 3, d00 = (f0 & 7) * 8, tl1 = f1 >> 3, d01 = (f1 & 7) * 8;
                *(u16x8*)&Kbuf[(tl0 * 64 + d00) ^ ((tl0 & 7) << 3)] = kst0;
                *(u16x8*)&Kbuf[(tl1 * 64 + d01) ^ ((tl1 & 7) << 3)] = kst1;
            }
        }
        if (p < 15) {                          // prefetch panel p+1
            if (WS) {
                const unsigned short* src = K2 + ((long)(bh * 16 + p + 1) << 13) + (tid << 3);
                kst0 = *(const u16x8*)src;
                kst1 = *(const u16x8*)(src + 4096);
            } else {
                const int f0 = tid, f1 = 512 + tid;
                const int tl0 = (p + 1) * 128 + (f0 >> 3), d00 = (f0 & 7) * 8;
                const int tl1 = (p + 1) * 128 + (f1 >> 3), d01 = (f1 & 7) * 8;
                #pragma unroll
                for (int j = 0; j < 8; ++j) kst0[j] = f2bf(k[((long)bh * DK + d00 + j) * S_LEN + tl0]);
                #pragma unroll
                for (int j = 0; j < 8; ++j) kst1[j] = f2bf(k[((long)bh * DK + d01 + j) * S_LEN + tl1]);
            }
        }
        __syncthreads();
        if ((p & 1) == 0) Mlds[(wave << 9) + (c << 6) + lane] = lm;   // save for pass 2
        const int b0 = (p & 1) * 4;
        #pragma unroll
        for (int cc = 0; cc < 4; ++cc) {
            u32x4 wv = qk_chunk(cc * 2);
            const unsigned mb = (unsigned)(lm >> (8 * (b0 + cc))) & 0xFFu;
            wv = apply_mask(wv, mb);
            rsum += ((bf2f((unsigned short)(wv.x & 0xFFFF)) + bf2f((unsigned short)(wv.x >> 16)))
                   + (bf2f((unsigned short)(wv.y & 0xFFFF)) + bf2f((unsigned short)(wv.y >> 16))))
                  + ((bf2f((unsigned short)(wv.z & 0xFFFF)) + bf2f((unsigned short)(wv.z >> 16)))
                   + (bf2f((unsigned short)(wv.w & 0xFFFF)) + bf2f((unsigned short)(wv.w >> 16))));
        }
        if ((p & 1) == 1 && p < 15) lm = redist(mask_burst(c + 1));   // next chunk's bits
    }

    rsum += __shfl_xor(rsum, 16);
    rsum += __shfl_xor(rsum, 32);              // lanes sharing m agree
    const float rinv = 1.0f / rsum;

    // ================================ PASS 2 ================================
    f32x4 cacc0 = {0,0,0,0}, cacc1 = {0,0,0,0}, cacc2 = {0,0,0,0}, cacc3 = {0,0,0,0};
    u16x8 vst0, vst1;
    if (WS) {
        const unsigned short* ks_ = K2 + ((long)(bh * 16) << 13) + (tid << 3);
        kst0 = *(const u16x8*)ks_;  kst1 = *(const u16x8*)(ks_ + 4096);
        const unsigned short* vs_ = V2 + ((long)(bh * 16) << 13) + (tid << 3);
        vst0 = *(const u16x8*)vs_;  vst1 = *(const u16x8*)(vs_ + 4096);
    } else {
        const int f0 = tid, f1 = 512 + tid;
        const int tl0 = f0 >> 3, d00 = (f0 & 7) * 8, tl1 = f1 >> 3, d01 = (f1 & 7) * 8;
        #pragma unroll
        for (int j = 0; j < 8; ++j) kst0[j] = f2bf(k[((long)bh * DK + d00 + j) * S_LEN + tl0]);
        #pragma unroll
        for (int j = 0; j < 8; ++j) kst1[j] = f2bf(k[((long)bh * DK + d01 + j) * S_LEN + tl1]);
        const int dv0 = f0 >> 3, t80 = (f0 & 7) * 8, dv1 = f1 >> 3, t81 = (f1 & 7) * 8;
        #pragma unroll
        for (int j = 0; j < 8; ++j) vst0[j] = f2bf(v[((long)bh * S_LEN + t80 + j) * DK + dv0]);
        #pragma unroll
        for (int j = 0; j < 8; ++j) vst1[j] = f2bf(v[((long)bh * S_LEN + t81 + j) * DK + dv1]);
    }
    float* aout = attn + (rowbase + m) * (long)S_LEN;
    for (int p = 0; p < 16; ++p) {
        const int c = p >> 1;
        __syncthreads();
        {
            if (WS) {
                *(u16x8*)&Kbuf[tid * 8]        = kst0;
                *(u16x8*)&Kbuf[4096 + tid * 8] = kst1;
                *(u16x8*)&Vbuf[tid * 8]        = vst0;
                *(u16x8*)&Vbuf[4096 + tid * 8] = vst1;
            } else {
                const int f0 = tid, f1 = 512 + tid;
                const int tl0 = f0 >> 3, d00 = (f0 & 7) * 8, tl1 = f1 >> 3, d01 = (f1 & 7) * 8;
                *(u16x8*)&Kbuf[(tl0 * 64 + d00) ^ ((tl0 & 7) << 3)] = kst0;
                *(u16x8*)&Kbuf[(tl1 * 64 + d01) ^ ((tl1 & 7) << 3)] = kst1;
                const int dv0 = f0 >> 3, t80 = (f0 & 7) * 8, dv1 = f1 >> 3, t81 = (f1 & 7) * 8;
                *(u16x8*)&Vbuf[(dv0 * 128 + t80) ^ ((dv0 & 7) << 3)] = vst0;
                *(u16x8*)&Vbuf[(dv1 * 128 + t81) ^ ((dv1 & 7) << 3)] = vst1;
            }
        }
        if (p < 15) {
            if (WS) {
                const unsigned short* ks_ = K2 + ((long)(bh * 16 + p + 1) << 13) + (tid << 3);
                kst0 = *(const u16x8*)ks_;  kst1 = *(const u16x8*)(ks_ + 4096);
                const unsigned short* vs_ = V2 + ((long)(bh * 16 + p + 1) << 13) + (tid << 3);
                vst0 = *(const u16x8*)vs_;  vst1 = *(const u16x8*)(vs_ + 4096);
            } else {
                const int f0 = tid, f1 = 512 + tid;
                const int tl0 = (p+1)*128 + (f0 >> 3), d00 = (f0 & 7) * 8;
                const int tl1 = (p+1)*128 + (f1 >> 3), d01 = (f1 & 7) * 8;
                #pragma unroll
                for (int j = 0; j < 8; ++j) kst0[j] = f2bf(k[((long)bh * DK + d00 + j) * S_LEN + tl0]);
                #pragma unroll
                for (int j = 0; j < 8; ++j) kst1[j] = f2bf(k[((long)bh * DK + d01 + j) * S_LEN + tl1]);
                const int dv0 = f0 >> 3, t80 = (p+1)*128 + (f0 & 7) * 8;
                const int dv1 = f1 >> 3, t81 = (p+1)*128 + (f1 & 7) * 8;
                #pragma unroll
                for (int j = 0; j < 8; ++j) vst0[j] = f2bf(v[((long)bh * S_LEN + t80 + j) * DK + dv0]);
                #pragma unroll
                for (int j = 0; j < 8; ++j) vst1[j] = f2bf(v[((long)bh * S_LEN + t81 + j) * DK + dv1]);
            }
        }
        __syncthreads();
        const u64 lm2 = Mlds[(wave << 9) + (c << 6) + lane];
        const int b0 = (p & 1) * 4;
        #pragma unroll
        for (int cc = 0; cc < 4; ++cc) {
            u32x4 wv = qk_chunk(cc * 2);
            const unsigned mb = (unsigned)(lm2 >> (8 * (b0 + cc))) & 0xFFu;
            wv = apply_mask(wv, mb);
            // attn store (normalized, nontemporal, 32B/lane contiguous)
            const int tb = p * 128 + cc * 32 + g * 8;
            f32x4 o0 = { bf2f((unsigned short)(wv.x & 0xFFFF)) * rinv,
                         bf2f((unsigned short)(wv.x >> 16))    * rinv,
                         bf2f((unsigned short)(wv.y & 0xFFFF)) * rinv,
                         bf2f((unsigned short)(wv.y >> 16))    * rinv };
            f32x4 o1 = { bf2f((unsigned short)(wv.z & 0xFFFF)) * rinv,
                         bf2f((unsigned short)(wv.z >> 16))    * rinv,
                         bf2f((unsigned short)(wv.w & 0xFFFF)) * rinv,
                         bf2f((unsigned short)(wv.w >> 16))    * rinv };
            __builtin_nontemporal_store(o0, (f32x4*)(aout + tb));
            __builtin_nontemporal_store(o1, (f32x4*)(aout + tb + 4));
            // PV: A = af (masked e), B = V from LDS image
            const bf16x8 af = __builtin_bit_cast(bf16x8, wv);
            #pragma unroll
            for (int dt = 0; dt < 4; ++dt) {
                const int d = dt * 16 + m;
                const int idx = (d * 128 + cc * 32 + g * 8) ^ ((d & 7) << 3);
                const bf16x8 bfv = *(const bf16x8*)&Vbuf[idx];
                if      (dt == 0) cacc0 = __builtin_amdgcn_mfma_f32_16x16x32_bf16(af, bfv, cacc0, 0, 0, 0);
                else if (dt == 1) cacc1 = __builtin_amdgcn_mfma_f32_16x16x32_bf16(af, bfv, cacc1, 0, 0, 0);
                else if (dt == 2) cacc2 = __builtin_amdgcn_mfma_f32_16x16x32_bf16(af, bfv, cacc2, 0, 0, 0);
                else              cacc3 = __builtin_amdgcn_mfma_f32_16x16x32_bf16(af, bfv, cacc3, 0, 0, 0);
            }
        }
    }

    // ---- ctx epilogue: lane (m,g) holds ctx[row 4g+i][dt*16+m] ----
    #pragma unroll
    for (int i = 0; i < 4; ++i) {
        const float ri = __shfl(rinv, 4 * g + i);
        float* cp = ctx + (rowbase + 4 * g + i) * DK + m;
        cp[ 0] = cacc0[i] * ri;
        cp[16] = cacc1[i] * ri;
        cp[32] = cacc2[i] * ri;
        cp[48] = cacc3[i] * ri;
    }
}

extern "C" void kernel_launch(void* const* d_in, const int* in_sizes, int n_in,
                              void* d_out, int out_size, void* d_ws, size_t ws_size,
                              hipStream_t stream)
{
    const float* q    = (const float*)d_in[0];
    const float* k    = (const float*)d_in[1];
    const float* v    = (const float*)d_in[2];
    const int*   mask = (const int*)d_in[3];

    float* ctx  = (float*)d_out;
    float* attn = ctx + (size_t)N_BH * S_LEN * DK;

    const size_t nel = (size_t)N_BH * S_LEN * DK;
    const bool use_ws = ws_size >= nel * 3 * sizeof(unsigned short);
    unsigned short* Q2 = (unsigned short*)d_ws;
    unsigned short* K2 = Q2 + nel;
    unsigned short* V2 = K2 + nel;

    const int nblocks = N_BH * (S_LEN / 128);                  // 512 = 2/CU

    if (use_ws) {
        prep_q<<<N_BH * 128, 128, 0, stream>>>(q, Q2);
        prep_k<<<N_BH * (S_LEN / 64), 256, 0, stream>>>(k, K2);
        prep_v<<<N_BH * (S_LEN / 64), 256, 0, stream>>>(v, V2);
        sdpa_main<true><<<nblocks, NTHREADS, 0, stream>>>(q, k, v, mask, Q2, K2, V2, ctx, attn);
    } else {
        sdpa_main<false><<<nblocks, NTHREADS, 0, stream>>>(q, k, v, mask,
                                                           nullptr, nullptr, nullptr, ctx, attn);
    }
}

// Round 11
// 501.383 us; speedup vs baseline: 1.1268x; 1.1268x over previous
//
#include <hip/hip_runtime.h>

#define S_LEN    2048
#define DK       64
#define N_BH     32
#define ROWS     16
#define NTHREADS 512

typedef float          f32x4  __attribute__((ext_vector_type(4)));
typedef int            i32x4  __attribute__((ext_vector_type(4)));
typedef short          bf16x8 __attribute__((ext_vector_type(8)));
typedef unsigned short u16x8  __attribute__((ext_vector_type(8)));
typedef unsigned int   u32x4  __attribute__((ext_vector_type(4)));

__device__ __forceinline__ unsigned short f2bf(float f) {
    unsigned u = __builtin_bit_cast(unsigned, f);
    u += 0x7fffu + ((u >> 16) & 1u);
    return (unsigned short)(u >> 16);
}
__device__ __forceinline__ float bf2f(unsigned short h) {
    unsigned u = ((unsigned)h) << 16;
    return __builtin_bit_cast(float, u);
}
__device__ __forceinline__ unsigned pack_bf2(float a, float b) {
    return (unsigned)f2bf(a) | ((unsigned)f2bf(b) << 16);
}

// ---------------- prep kernels: fragment-ordered bf16 layouts in d_ws ----------------
// K2[((((bh*128+t16)*2+ks)*4+g)*16+m)*8 + j] = k[bh][d=ks*32+g*8+j][t=t16*16+m]
__global__ void prep_k(const float* __restrict__ k, unsigned short* __restrict__ K2) {
    __shared__ float t[64][65];
    const int bh = blockIdx.x >> 5, s0 = (blockIdx.x & 31) << 6;
    const int tx = threadIdx.x;
    const float* kb = k + (long)bh * DK * S_LEN;
    #pragma unroll
    for (int i = 0; i < 16; ++i) {
        const int d = (i << 2) + (tx >> 6), s = tx & 63;
        t[d][s] = kb[(long)d * S_LEN + s0 + s];
    }
    __syncthreads();
    #pragma unroll
    for (int it = 0; it < 2; ++it) {
        const int flat = it * 256 + tx;        // m(4)|g(2)|ks(1)|t16g(2)
        const int m = flat & 15, g = (flat >> 4) & 3, ks = (flat >> 6) & 1, t16g = flat >> 7;
        const int sl = t16g * 16 + m;
        const int d0 = ks * 32 + g * 8;
        u16x8 o;
        #pragma unroll
        for (int j = 0; j < 8; ++j) o[j] = f2bf(t[d0 + j][sl]);
        const long idx = ((((long)(bh * 128 + (s0 >> 4) + t16g) * 2 + ks) * 4 + g) * 16 + m) * 8;
        *(u16x8*)(K2 + idx) = o;
    }
}

// V2[((bh*256+tbi)*64+d)*8 + j] = v[bh][t=tbi*8+j][d]
__global__ void prep_v(const float* __restrict__ v, unsigned short* __restrict__ V2) {
    __shared__ float t[64][65];
    const int bh = blockIdx.x >> 5, s0 = (blockIdx.x & 31) << 6;
    const int tx = threadIdx.x;
    #pragma unroll
    for (int i = 0; i < 16; ++i) {
        const int s = (i << 2) + (tx >> 6), d = tx & 63;
        t[s][d] = v[((long)bh * S_LEN + s0 + s) * DK + d];
    }
    __syncthreads();
    #pragma unroll
    for (int it = 0; it < 2; ++it) {
        const int flat = it * 256 + tx;        // d(6)|tbl(3)
        const int d = flat & 63, tbl = flat >> 6;
        u16x8 o;
        #pragma unroll
        for (int j = 0; j < 8; ++j) o[j] = f2bf(t[tbl * 8 + j][d]);
        const long idx = (((long)(bh * 256 + (s0 >> 3) + tbl) * 64) + d) * 8;
        *(u16x8*)(V2 + idx) = o;
    }
}

// ---------------------------- main attention kernel ----------------------------
// Recompute-flash: pass1 = QK^T+exp+mask -> rsum (1 barrier); pass2 = recompute,
// normalize immediately, stream attn + PV. Mask lives in registers across both.
template <bool WS>
__global__ __launch_bounds__(NTHREADS, 4)
void sdpa_main(const float* __restrict__ q, const float* __restrict__ k,
               const float* __restrict__ v, const int* __restrict__ mask,
               const unsigned short* __restrict__ K2,
               const unsigned short* __restrict__ V2,
               float* __restrict__ ctx, float* __restrict__ attn)
{
    __shared__ float rowsum[ROWS];

    const int bid  = blockIdx.x;
    const int bh   = bid & (N_BH - 1);         // head-minor: K2/V2 of 4 heads per XCD L2
    const int qt   = bid >> 5;
    const int tid  = threadIdx.x;
    const int wave = tid >> 6;
    const int lane = tid & 63;
    const int m    = lane & 15;
    const int g    = lane >> 4;
    const long rowbase = (long)bh * S_LEN + qt * ROWS;
    const int tw   = wave << 8;                // this wave's 256-col slice

    if (tid < ROWS) rowsum[tid] = 0.0f;

    // ---- mask burst: 16 coalesced 1KB nontemporal loads -> 64 bits/lane ----
    unsigned mlo = 0, mhi = 0;                 // nibble r = row r, cols tw+4*lane..+3
    {
        const int* mbase = mask + rowbase * S_LEN + tw + 4 * lane;
        #pragma unroll
        for (int r = 0; r < 16; ++r) {
            const i32x4 mk = __builtin_nontemporal_load((const i32x4*)(mbase + (long)r * S_LEN));
            const unsigned nib = (mk.x ? 1u : 0u) | (mk.y ? 2u : 0u)
                               | (mk.z ? 4u : 0u) | (mk.w ? 8u : 0u);
            if (r < 8) mlo |= nib << (r * 4);
            else       mhi |= nib << ((r - 8) * 4);
        }
    }

    // ---- Q fragment (B operand): Q[col=m][k=ks*32+g*8+j] ----
    bf16x8 qfrag[2];
    {
        const float* qp = q + (rowbase + m) * DK;
        #pragma unroll
        for (int ks = 0; ks < 2; ++ks) {
            const float* p = qp + ks * 32 + g * 8;
            f32x4 x0 = *(const f32x4*)p, x1 = *(const f32x4*)(p + 4);
            qfrag[ks][0]=(short)f2bf(x0.x); qfrag[ks][1]=(short)f2bf(x0.y);
            qfrag[ks][2]=(short)f2bf(x0.z); qfrag[ks][3]=(short)f2bf(x0.w);
            qfrag[ks][4]=(short)f2bf(x1.x); qfrag[ks][5]=(short)f2bf(x1.y);
            qfrag[ks][6]=(short)f2bf(x1.z); qfrag[ks][7]=(short)f2bf(x1.w);
        }
    }

    // QK^T for one 16-col tile ct; returns masked e = exp(s/8) (0 where masked).
    // acc[i] = S[q=m][t = tw + ct*16 + 4g + i]   (swapped-MFMA layout, r6-r8 verified)
    auto qk_tile = [&](int ct) -> f32x4 {
        f32x4 acc = {0.f, 0.f, 0.f, 0.f};
        #pragma unroll
        for (int ks = 0; ks < 2; ++ks) {
            bf16x8 kfrag;
            if (WS) {
                const unsigned short* kp = K2
                    + (((long)(bh * 128 + wave * 16 + ct) * 2 + ks) << 9)
                    + (lane << 3);             // coalesced: base + lane*16B
                kfrag = *(const bf16x8*)kp;
            } else {
                const int tk = tw + ct * 16 + m;
                const float* kp = k + (long)bh * DK * S_LEN + (long)(ks * 32 + g * 8) * S_LEN + tk;
                #pragma unroll
                for (int j = 0; j < 8; ++j) kfrag[j] = (short)f2bf(kp[(long)j * S_LEN]);
            }
            acc = __builtin_amdgcn_mfma_f32_16x16x32_bf16(kfrag, qfrag[ks], acc, 0, 0, 0);
        }
        // mask bits for (row m, cols ct*16+4g+0..3) live in lane ct*4+g, nibble m
        const int sL = ct * 4 + g;
        const unsigned a = (unsigned)__shfl((int)mlo, sL);
        const unsigned b = (unsigned)__shfl((int)mhi, sL);
        const unsigned nib = (((m & 8) ? b : a) >> ((m & 7) * 4)) & 0xFu;
        f32x4 e;
        e.x = (nib & 1u) ? 0.0f : __expf(acc[0] * 0.125f);
        e.y = (nib & 2u) ? 0.0f : __expf(acc[1] * 0.125f);
        e.z = (nib & 4u) ? 0.0f : __expf(acc[2] * 0.125f);
        e.w = (nib & 8u) ? 0.0f : __expf(acc[3] * 0.125f);
        return e;
    };

    // ================= pass 1: row sums (no stores) =================
    float rsum = 0.0f;
    #pragma unroll
    for (int ct = 0; ct < 16; ++ct) {
        const f32x4 e = qk_tile(ct);
        rsum += (e.x + e.y) + (e.z + e.w);
    }
    rsum += __shfl_xor(rsum, 16);
    rsum += __shfl_xor(rsum, 32);              // lanes sharing m agree
    __syncthreads();                           // rowsum init visible
    if (lane < 16) atomicAdd(&rowsum[lane], rsum);
    __syncthreads();
    const float rinv = 1.0f / rowsum[m];

    // ================= pass 2: recompute -> attn stream + PV =================
    const int srcA = ((g & 1) << 5) + m;
    const int srcB = srcA + 16;
    const int hi   = g >> 1;
    f32x4 cacc0 = {0,0,0,0}, cacc1 = {0,0,0,0}, cacc2 = {0,0,0,0}, cacc3 = {0,0,0,0};
    float* aout = attn + (rowbase + m) * (long)S_LEN;

    #pragma unroll
    for (int kt = 0; kt < 8; ++kt) {
        const f32x4 ee = qk_tile(2 * kt);
        const f32x4 eo = qk_tile(2 * kt + 1);
        const unsigned pk0e = pack_bf2(ee.x, ee.y), pk1e = pack_bf2(ee.z, ee.w);
        const unsigned pk0o = pack_bf2(eo.x, eo.y), pk1o = pack_bf2(eo.z, eo.w);
        // shfl: af = P[row m][cols tb..tb+7], tb = tw + kt*32 + g*8  (r6-r8 verified)
        const unsigned a0e = (unsigned)__shfl((int)pk0e, srcA);
        const unsigned a0o = (unsigned)__shfl((int)pk0o, srcA);
        const unsigned a1e = (unsigned)__shfl((int)pk1e, srcA);
        const unsigned a1o = (unsigned)__shfl((int)pk1o, srcA);
        const unsigned a2e = (unsigned)__shfl((int)pk0e, srcB);
        const unsigned a2o = (unsigned)__shfl((int)pk0o, srcB);
        const unsigned a3e = (unsigned)__shfl((int)pk1e, srcB);
        const unsigned a3o = (unsigned)__shfl((int)pk1o, srcB);
        const u32x4 wv = { hi ? a0o : a0e, hi ? a1o : a1e,
                           hi ? a2o : a2e, hi ? a3o : a3e };
        // ---- attn stores: normalized, nontemporal, 32B/lane contiguous ----
        const int tb = tw + (kt << 5) + (g << 3);
        f32x4 o0 = { bf2f((unsigned short)(wv.x & 0xFFFF)) * rinv,
                     bf2f((unsigned short)(wv.x >> 16))    * rinv,
                     bf2f((unsigned short)(wv.y & 0xFFFF)) * rinv,
                     bf2f((unsigned short)(wv.y >> 16))    * rinv };
        f32x4 o1 = { bf2f((unsigned short)(wv.z & 0xFFFF)) * rinv,
                     bf2f((unsigned short)(wv.z >> 16))    * rinv,
                     bf2f((unsigned short)(wv.w & 0xFFFF)) * rinv,
                     bf2f((unsigned short)(wv.w >> 16))    * rinv };
        __builtin_nontemporal_store(o0, (f32x4*)(aout + tb));
        __builtin_nontemporal_store(o1, (f32x4*)(aout + tb + 4));
        // ---- PV MFMAs: A = af (unnormalized masked e), B = V[col=dt*16+m][k=tb+j] ----
        const bf16x8 af = __builtin_bit_cast(bf16x8, wv);
        #pragma unroll
        for (int dt = 0; dt < 4; ++dt) {
            bf16x8 bfv;
            if (WS) {
                const unsigned short* vp2 = V2
                    + ((((long)(bh * 256 + (wave << 5) + (kt << 2) + g)) << 6) + dt * 16 + m) * 8;
                bfv = *(const bf16x8*)vp2;
            } else {
                const float* vp = v + ((long)bh * S_LEN + tb) * DK + dt * 16 + m;
                #pragma unroll
                for (int j = 0; j < 8; ++j) bfv[j] = (short)f2bf(vp[j * DK]);
            }
            if      (dt == 0) cacc0 = __builtin_amdgcn_mfma_f32_16x16x32_bf16(af, bfv, cacc0, 0, 0, 0);
            else if (dt == 1) cacc1 = __builtin_amdgcn_mfma_f32_16x16x32_bf16(af, bfv, cacc1, 0, 0, 0);
            else if (dt == 2) cacc2 = __builtin_amdgcn_mfma_f32_16x16x32_bf16(af, bfv, cacc2, 0, 0, 0);
            else              cacc3 = __builtin_amdgcn_mfma_f32_16x16x32_bf16(af, bfv, cacc3, 0, 0, 0);
        }
    }

    // ---- ctx epilogue: lane (m,g) holds D[row 4g+i][col dt*16+m]; per-wave partial ----
    // waves hold disjoint t-slices -> cross-wave sum via global atomic-free: each wave
    // owns full rows? No: all waves share rows, partials must sum. Use LDS-free trick:
    // accumulate via __shfl is wrong; use global atomics? ctx small (17MB): do LDS pass.
    __shared__ float ctxlds[ROWS * DK];
    for (int i = tid; i < ROWS * DK; i += NTHREADS) ctxlds[i] = 0.0f;
    __syncthreads();
    #pragma unroll
    for (int i = 0; i < 4; ++i) {
        atomicAdd(&ctxlds[(4 * g + i) * DK +  0 + m], cacc0[i]);
        atomicAdd(&ctxlds[(4 * g + i) * DK + 16 + m], cacc1[i]);
        atomicAdd(&ctxlds[(4 * g + i) * DK + 32 + m], cacc2[i]);
        atomicAdd(&ctxlds[(4 * g + i) * DK + 48 + m], cacc3[i]);
    }
    __syncthreads();
    for (int i = tid; i < ROWS * DK; i += NTHREADS) {
        const int rr = i >> 6, dd = i & 63;
        ctx[(rowbase + rr) * DK + dd] = ctxlds[i] / rowsum[rr];
    }
}

extern "C" void kernel_launch(void* const* d_in, const int* in_sizes, int n_in,
                              void* d_out, int out_size, void* d_ws, size_t ws_size,
                              hipStream_t stream)
{
    const float* q    = (const float*)d_in[0];
    const float* k    = (const float*)d_in[1];
    const float* v    = (const float*)d_in[2];
    const int*   mask = (const int*)d_in[3];

    float* ctx  = (float*)d_out;
    float* attn = ctx + (size_t)N_BH * S_LEN * DK;

    const size_t nel = (size_t)N_BH * S_LEN * DK;
    const bool use_ws = ws_size >= nel * 2 * sizeof(unsigned short);   // 16.8 MB
    unsigned short* K2 = (unsigned short*)d_ws;
    unsigned short* V2 = K2 + nel;

    const int nblocks = N_BH * (S_LEN / ROWS);                 // 4096

    if (use_ws) {
        prep_k<<<N_BH * (S_LEN / 64), 256, 0, stream>>>(k, K2);
        prep_v<<<N_BH * (S_LEN / 64), 256, 0, stream>>>(v, V2);
        sdpa_main<true><<<nblocks, NTHREADS, 0, stream>>>(q, k, v, mask, K2, V2, ctx, attn);
    } else {
        sdpa_main<false><<<nblocks, NTHREADS, 0, stream>>>(q, k, v, mask,
                                                           nullptr, nullptr, ctx, attn);
    }
}